// Round 7
// baseline (427.759 us; speedup 1.0000x reference)
//
#include <hip/hip_runtime.h>
#include <math.h>

#define BB 4
#define NN 4096
#define KK 16
#define CIN 32
#define COUT 64
#define BN_INV 0.9999950000375f

#define RS 32    // candidate ranges per query
#define PCH 128  // candidates per range (NN/RS)
#define PK 16    // prefilter top-K per range
#define NK2 24   // candidates sent to fp64 rerank

typedef float f32x2 __attribute__((ext_vector_type(2)));

// ---------------- P0: derived W1 weights ----------------
__global__ void p0_weights(const float* __restrict__ W1,
                           float* __restrict__ Aw, float* __restrict__ Bw,
                           float* __restrict__ w1d) {
    int t = threadIdx.x;
    for (int i = t; i < 64 * 32; i += 256) {
        int o = i >> 5, c = i & 31;
        Aw[i] = W1[o * 128 + c] - W1[o * 128 + 64 + c];
        Bw[i] = W1[o * 128 + 32 + c] + W1[o * 128 + 64 + c];
    }
    if (t < 64) {
        float s = 0.f;
        for (int c = 96; c < 128; ++c) s += W1[t * 128 + c];
        w1d[t] = s;
    }
}

// ---------------- P1: transpose features to [B,N,32] + fp32/fp64 norms ----------------
__global__ void p1_transpose(const float* __restrict__ f, float* __restrict__ pT,
                             float* __restrict__ sq32, double* __restrict__ sq64) {
    int g = blockIdx.x * 256 + threadIdx.x;  // b*N + n
    int b = g >> 12, n = g & (NN - 1);
    float v[CIN];
#pragma unroll
    for (int c = 0; c < CIN; ++c) v[c] = f[(b * CIN + c) * NN + n];
#pragma unroll
    for (int c = 0; c < CIN; ++c) pT[(size_t)g * CIN + c] = v[c];
    // 4-accumulator chain — BITWISE identical to knn_prefilter's pk_fma dot chain
    float a0 = 0.f, a1 = 0.f, a2 = 0.f, a3 = 0.f;
#pragma unroll
    for (int c4 = 0; c4 < 8; ++c4) {
        a0 = fmaf(v[4 * c4 + 0], v[4 * c4 + 0], a0);
        a1 = fmaf(v[4 * c4 + 1], v[4 * c4 + 1], a1);
        a2 = fmaf(v[4 * c4 + 2], v[4 * c4 + 2], a2);
        a3 = fmaf(v[4 * c4 + 3], v[4 * c4 + 3], a3);
    }
    sq32[g] = (a0 + a1) + (a2 + a3);
    // sequential fp64 chain — must match knn_final's rerank chains
    double s64 = 0.0;
#pragma unroll
    for (int c = 0; c < CIN; ++c) s64 = fma((double)v[c], (double)v[c], s64);
    sq64[g] = s64;
}

// ---------------- P2: per-point projections ctrA = A*p, nbrB = B*p ----------------
__global__ __launch_bounds__(256) void p2_proj(const float* __restrict__ pT,
                                               const float* __restrict__ Aw,
                                               const float* __restrict__ Bw,
                                               float* __restrict__ ctrA,
                                               float* __restrict__ nbrB) {
    __shared__ float sA[32 * 64], sB[32 * 64];
    for (int i = threadIdx.x; i < 2048; i += 256) {
        int o = i >> 5, c = i & 31;
        sA[c * 64 + o] = Aw[i];
        sB[c * 64 + o] = Bw[i];
    }
    __syncthreads();
    int g = blockIdx.x * 256 + threadIdx.x;  // (b*N+n)*64 + o
    int o = g & 63;
    int pn = g >> 6;
    const float* p = pT + (size_t)pn * 32;
    float a = 0.f, bb = 0.f;
#pragma unroll
    for (int c = 0; c < 32; ++c) {
        float pv = p[c];
        a = fmaf(sA[c * 64 + o], pv, a);
        bb = fmaf(sB[c * 64 + o], pv, bb);
    }
    ctrA[g] = a;
    nbrB[g] = bb;
}

// ---------------- KNN prefilter: LDS-staged tile + pk_fma dot + packed-key top-16 ----
__global__ __launch_bounds__(256) void knn_prefilter(const float* __restrict__ pT,
                                                     const float* __restrict__ sq32,
                                                     unsigned* __restrict__ pkey) {
    __shared__ float tile[PCH * 32];   // 16 KB candidate tile
    __shared__ float tsq[PCH];         // 512 B norms
    int tid = threadIdx.x;
    int n = blockIdx.x * 256 + tid;    // global point id (b*N+nb)
    int b = n >> 12;
    const float* pb = pT + ((size_t)(b << 12)) * 32;
    int m0 = blockIdx.y * PCH;

    // stage this block's candidate range into LDS (coalesced)
    {
        const float4* src = (const float4*)(pb + (size_t)m0 * 32);
        float4* dst = (float4*)tile;
#pragma unroll
        for (int i = 0; i < (PCH * 8) / 256; ++i) dst[tid + 256 * i] = src[tid + 256 * i];
        if (tid < PCH) tsq[tid] = sq32[(b << 12) + m0 + tid];
    }

    // query vector as f32x2 pairs
    f32x2 qv[16];
    {
        const float4* q4 = (const float4*)(pT + (size_t)n * 32);
#pragma unroll
        for (int c4 = 0; c4 < 8; ++c4) {
            float4 t = q4[c4];
            qv[2 * c4 + 0] = (f32x2){t.x, t.y};
            qv[2 * c4 + 1] = (f32x2){t.z, t.w};
        }
    }
    float negsqn = -sq32[n];
    unsigned key[PK];
#pragma unroll
    for (int i = 0; i < PK; ++i) key[i] = 0u;

    __syncthreads();

#pragma unroll 2
    for (int mm = 0; mm < PCH; ++mm) {
        const float4* row = (const float4*)(tile + mm * 32);  // wave-uniform -> broadcast
        f32x2 a01 = {0.f, 0.f}, a23 = {0.f, 0.f};
#pragma unroll
        for (int c4 = 0; c4 < 8; ++c4) {
            float4 t = row[c4];
            a01 = __builtin_elementwise_fma((f32x2){t.x, t.y}, qv[2 * c4 + 0], a01);
            a23 = __builtin_elementwise_fma((f32x2){t.z, t.w}, qv[2 * c4 + 1], a23);
        }
        float dot = (a01.x + a01.y) + (a23.x + a23.y);
        // self: dot == sq32[n] bitwise (identical chain); fmaf(2,dot,-2*sq) == 0 exactly
        float d = fmaf(2.f, dot, negsqn - tsq[mm]);
        unsigned u = __float_as_uint(d);
        unsigned k32 = u ^ (unsigned)(((int)u >> 31) | 0x80000000);
        unsigned cv = (k32 & 0xFFFFF000u) | (unsigned)(4095 - (m0 + mm));
        // branchless 16-deep sorted insert
#pragma unroll
        for (int j = 0; j < PK; ++j) {
            unsigned vj = key[j];
            unsigned hi = cv > vj ? cv : vj;
            unsigned lo = cv > vj ? vj : cv;
            key[j] = hi; cv = lo;
        }
    }
    // layout [r][k][B*N] for coalesced read in knn_final
    size_t base = (size_t)blockIdx.y * PK * (BB * NN) + n;
#pragma unroll
    for (int i = 0; i < PK; ++i) pkey[base + (size_t)i * (BB * NN)] = key[i];
}

// ---------------- KNN final: key-select top-24, fp64 exact rerank -> top-16 ----------------
__global__ __launch_bounds__(64) void knn_final(const float* __restrict__ pT,
                                                const double* __restrict__ sq64,
                                                const unsigned* __restrict__ pkey,
                                                int* __restrict__ fidx,
                                                float* __restrict__ fdist) {
    int n = blockIdx.x * 64 + threadIdx.x;
    int b = n >> 12;
    const float* pb = pT + ((size_t)(b << 12)) * 32;
    const double* sqb = sq64 + (b << 12);

    unsigned sk[NK2];
#pragma unroll
    for (int i = 0; i < NK2; ++i) sk[i] = 0u;
    for (int r = 0; r < RS; ++r) {
        unsigned kv[PK];
#pragma unroll
        for (int k = 0; k < PK; ++k)
            kv[k] = pkey[(size_t)(r * PK + k) * (BB * NN) + n];  // coalesced batch
        for (int k = 0; k < PK; ++k) {
            unsigned cv = kv[k];
            if (__all(cv <= sk[NK2 - 1])) break;  // lane-keys descend within range
#pragma unroll
            for (int j = 0; j < NK2; ++j) {
                unsigned vj = sk[j];
                unsigned hi = cv > vj ? cv : vj;
                unsigned lo = cv > vj ? vj : cv;
                sk[j] = hi; cv = lo;
            }
        }
    }

    // fp64 exact rerank of the NK2 survivors
    double qv[32];
    const float4* q4 = (const float4*)(pT + (size_t)n * 32);
#pragma unroll
    for (int c4 = 0; c4 < 8; ++c4) {
        float4 t = q4[c4];
        qv[4 * c4] = (double)t.x; qv[4 * c4 + 1] = (double)t.y;
        qv[4 * c4 + 2] = (double)t.z; qv[4 * c4 + 3] = (double)t.w;
    }
    double sqn = 0.0;
#pragma unroll
    for (int c = 0; c < 32; ++c) sqn = fma(qv[c], qv[c], sqn);

    double dv[16];
    int di[16];
#pragma unroll
    for (int i = 0; i < 16; ++i) { dv[i] = -1e300; di[i] = 0x7fffffff; }
#pragma unroll
    for (int u = 0; u < NK2; ++u) {
        int m = 4095 - (int)(sk[u] & 0xFFFu);
        const float4* row = (const float4*)(pb + (size_t)m * 32);
        double dot = 0.0;
#pragma unroll
        for (int c4 = 0; c4 < 8; ++c4) {
            float4 t = row[c4];
            dot = fma((double)t.x, qv[4 * c4], dot);
            dot = fma((double)t.y, qv[4 * c4 + 1], dot);
            dot = fma((double)t.z, qv[4 * c4 + 2], dot);
            dot = fma((double)t.w, qv[4 * c4 + 3], dot);
        }
        double d = 2.0 * dot - sqn - sqb[m];  // self -> exactly 0
        if (d > dv[15] || (d == dv[15] && m < di[15])) {
            double cv = d; int ci = m;
#pragma unroll
            for (int j = 0; j < 16; ++j) {
                bool c = (cv > dv[j]) || (cv == dv[j] && ci < di[j]);
                double nv = c ? cv : dv[j]; double nc = c ? dv[j] : cv;
                int ni = c ? ci : di[j];    int nj = c ? di[j] : ci;
                dv[j] = nv; cv = nc; di[j] = ni; ci = nj;
            }
        }
    }
#pragma unroll
    for (int i = 0; i < 16; ++i) {
        fdist[(size_t)n * 16 + i] = (float)dv[i];
        fidx[(size_t)n * 16 + i] = di[i];
    }
}

// ---------------- Fused main pipeline: LDS-staged weights, 16n x 16k per block ----------
__global__ __launch_bounds__(256) void fuse_kernel(
    const float* __restrict__ coords, const float* __restrict__ feat,
    const int* __restrict__ knn_idx, const float* __restrict__ knn_dist,
    const float* __restrict__ W2, const float* __restrict__ W3,
    const float* __restrict__ W4, const float* __restrict__ W5,
    const float* __restrict__ g1, const float* __restrict__ b1,
    const float* __restrict__ g2, const float* __restrict__ b2,
    const float* __restrict__ g3, const float* __restrict__ b3,
    const float* __restrict__ g4, const float* __restrict__ b4,
    const float* __restrict__ g5, const float* __restrict__ b5,
    const float* __restrict__ ctrA, const float* __restrict__ nbrB,
    const float* __restrict__ w1d, const int* __restrict__ fidx,
    const float* __restrict__ fdist, float* __restrict__ out) {
    __shared__ float sW5[32 * 96];          // 12 KB
    __shared__ float sW3[32 * 16];          // rows padded 13->16
    __shared__ float sW4[32 * 16];
    __shared__ float sW2[3 * 64];
    __shared__ float sg1[64], sb1[64], sw1d[64];
    __shared__ float sg3[32], sb3[32], sg4[32], sb4[32], sg5[32], sb5[32];
    __shared__ float sg2[4], sb2[4];
    __shared__ float sCA[16 * 64];          // 4 KB: ctrA rows for this block's 16 ns
    __shared__ float sFeat[16 * 32];        // 2 KB
    __shared__ float sCrd[16 * 4];

    int tid = threadIdx.x;
    int b = blockIdx.x >> 8;                 // blockIdx.x / (NN/16 * ... ) : 256 blocks per batch*... (16384 blocks total; 4096 per b)
    int nbase = (blockIdx.x & 255) * 16;     // 256 blocks per b cover N=4096 in steps of 16
    // NOTE: grid is BB * (NN/16) = 1024 blocks? -> we use 2D grid instead; see launch.
    b = blockIdx.y;
    nbase = blockIdx.x * 16;

    // ---- stage weights ----
    for (int i = tid; i < 3072; i += 256) sW5[i] = W5[i];
    for (int i = tid; i < 416; i += 256) {
        int c = i / 13, j = i - c * 13;
        sW3[c * 16 + j] = W3[i];
        sW4[c * 16 + j] = W4[i];
    }
    if (tid < 192) sW2[tid] = W2[tid];
    if (tid < 64) { sg1[tid] = g1[tid] * BN_INV; sb1[tid] = b1[tid]; sw1d[tid] = w1d[tid]; }
    if (tid >= 64 && tid < 96) {
        int c = tid - 64;
        sg3[c] = g3[c] * BN_INV; sb3[c] = b3[c];
        sg4[c] = g4[c] * BN_INV; sb4[c] = b4[c];
        sg5[c] = g5[c] * BN_INV; sb5[c] = b5[c];
    }
    if (tid >= 96 && tid < 99) { sg2[tid - 96] = g2[tid - 96] * BN_INV; sb2[tid - 96] = b2[tid - 96]; }

    // ---- stage per-n operands ----
    {
        size_t caBase = ((size_t)b * NN + nbase) * 64;
        ((float4*)sCA)[tid] = ((const float4*)(ctrA + caBase))[tid];  // 256 float4 = 1024 f
        for (int i = tid; i < 512; i += 256) {
            int c = i >> 4, nn = i & 15;
            sFeat[nn * 32 + c] = feat[((size_t)b * 32 + c) * NN + nbase + nn];
        }
        if (tid < 48) {
            int nn = tid / 3, j = tid - nn * 3;
            sCrd[nn * 4 + j] = coords[((size_t)b * NN + nbase + nn) * 3 + j];
        }
    }
    __syncthreads();

    int k = tid & 15, n0 = tid >> 4;
    int pn = b * NN + nbase + n0;

    int fnb = fidx[(size_t)pn * 16 + k];
    float fd = fdist[(size_t)pn * 16 + k];
    const float4* nB4 = (const float4*)(nbrB + ((size_t)b * NN + fnb) * 64);
    const float4* cA4 = (const float4*)(sCA + n0 * 64);

    // features_knn (64) = leaky(BN(W1 . edge)); y order: (cA + nB) + w1d*fd
    float fk[64];
#pragma unroll
    for (int o4 = 0; o4 < 16; ++o4) {
        float4 ca = cA4[o4];
        float4 nb = nB4[o4];
        float4 wd = ((const float4*)sw1d)[o4];
        float4 gg = ((const float4*)sg1)[o4];
        float4 bb = ((const float4*)sb1)[o4];
        float y0 = ca.x + nb.x + wd.x * fd;
        float y1 = ca.y + nb.y + wd.y * fd;
        float y2 = ca.z + nb.z + wd.z * fd;
        float y3 = ca.w + nb.w + wd.w * fd;
        float v0 = fmaf(gg.x, y0, bb.x);
        float v1 = fmaf(gg.y, y1, bb.y);
        float v2 = fmaf(gg.z, y2, bb.z);
        float v3 = fmaf(gg.w, y3, bb.w);
        fk[4 * o4 + 0] = v0 > 0.f ? v0 : 0.2f * v0;
        fk[4 * o4 + 1] = v1 > 0.f ? v1 : 0.2f * v1;
        fk[4 * o4 + 2] = v2 > 0.f ? v2 : 0.2f * v2;
        fk[4 * o4 + 3] = v3 > 0.f ? v3 : 0.2f * v3;
    }

    float cq[3], cn_[3];
#pragma unroll
    for (int j = 0; j < 3; ++j) cq[j] = sCrd[n0 * 4 + j];
    int cnb = knn_idx[(size_t)pn * 16 + k];
#pragma unroll
    for (int j = 0; j < 3; ++j) cn_[j] = coords[((size_t)b * NN + cnb) * 3 + j];
    float kd = knn_dist[(size_t)pn * 16 + k];

    float cp[13];
#pragma unroll
    for (int j = 0; j < 3; ++j) {
        float a = 0.f;
        const float4* w4p = (const float4*)(sW2 + j * 64);
#pragma unroll
        for (int o4 = 0; o4 < 16; ++o4) {
            float4 w = w4p[o4];
            a = fmaf(w.x, fk[4 * o4 + 0], a);
            a = fmaf(w.y, fk[4 * o4 + 1], a);
            a = fmaf(w.z, fk[4 * o4 + 2], a);
            a = fmaf(w.w, fk[4 * o4 + 3], a);
        }
        float t = fmaf(sg2[j], a, sb2[j]);
        t = t > 0.f ? t : __expf(t) - 1.f;  // elu
        cp[j] = cq[j];
        cp[3 + j] = cn_[j];
        cp[6 + j] = cq[j] - cn_[j];
        cp[10 + j] = t + cq[j];
    }
    cp[9] = kd;

    float fe[32];
#pragma unroll
    for (int c = 0; c < 32; ++c) {
        float a3 = 0.f, a4 = 0.f;
        const float* w3r = sW3 + c * 16;
        const float* w4r = sW4 + c * 16;
#pragma unroll
        for (int j = 0; j < 13; ++j) {
            a3 = fmaf(w3r[j], cp[j], a3);
            a4 = fmaf(w4r[j], cp[j], a4);
        }
        float po = fmaf(sg3[c], a3, sb3[c]);
        po = po > 0.f ? po : __expf(po) - 1.f;
        fe[c] = po + sFeat[n0 * 32 + c];
        float op = fmaf(sg4[c], a4, sb4[c]);
        op = op > 0.f ? op : __expf(op) - 1.f;
        out[(((size_t)b * 64 + c) * NN + nbase + n0) * 16 + k] = op;
    }

#pragma unroll
    for (int c = 0; c < 32; ++c) {
        float a5 = 0.f;
        const float4* w5r = (const float4*)(sW5 + c * 96);
#pragma unroll
        for (int o4 = 0; o4 < 16; ++o4) {
            float4 w = w5r[o4];
            a5 = fmaf(w.x, fk[4 * o4 + 0], a5);
            a5 = fmaf(w.y, fk[4 * o4 + 1], a5);
            a5 = fmaf(w.z, fk[4 * o4 + 2], a5);
            a5 = fmaf(w.w, fk[4 * o4 + 3], a5);
        }
#pragma unroll
        for (int j4 = 0; j4 < 8; ++j4) {
            float4 w = w5r[16 + j4];
            a5 = fmaf(w.x, fe[4 * j4 + 0], a5);
            a5 = fmaf(w.y, fe[4 * j4 + 1], a5);
            a5 = fmaf(w.z, fe[4 * j4 + 2], a5);
            a5 = fmaf(w.w, fe[4 * j4 + 3], a5);
        }
        float v = fmaf(sg5[c], a5, sb5[c]);
        v = v > 0.f ? v : __expf(v) - 1.f;
        out[(((size_t)b * 64 + 32 + c) * NN + nbase + n0) * 16 + k] = v;
    }
}

extern "C" void kernel_launch(void* const* d_in, const int* in_sizes, int n_in,
                              void* d_out, int out_size, void* d_ws, size_t ws_size,
                              hipStream_t stream) {
    const float* coords   = (const float*)d_in[0];
    const float* features = (const float*)d_in[1];
    const int*   knn_idx  = (const int*)d_in[2];
    const float* knn_dist = (const float*)d_in[3];
    const float* W1 = (const float*)d_in[4];
    const float* W2 = (const float*)d_in[5];
    const float* W3 = (const float*)d_in[6];
    const float* W4 = (const float*)d_in[7];
    const float* W5 = (const float*)d_in[8];
    const float* g1 = (const float*)d_in[9];
    const float* b1 = (const float*)d_in[10];
    const float* g2 = (const float*)d_in[11];
    const float* b2 = (const float*)d_in[12];
    const float* g3 = (const float*)d_in[13];
    const float* b3 = (const float*)d_in[14];
    const float* g4 = (const float*)d_in[15];
    const float* b4 = (const float*)d_in[16];
    const float* g5 = (const float*)d_in[17];
    const float* b5 = (const float*)d_in[18];
    float* out = (float*)d_out;

    // workspace layout (float slots)
    float*  pT    = (float*)d_ws;                  // 524288
    float*  sq32  = pT + BB * NN * 32;             // 16384
    double* sq64  = (double*)(sq32 + BB * NN);     // 16384 doubles (32768 slots)
    float*  fdist = (float*)(sq64 + BB * NN);      // 262144
    int*    fidx  = (int*)(fdist + BB * NN * 16);  // 262144
    float*  Aw    = (float*)(fidx + BB * NN * 16); // 2048
    float*  Bw    = Aw + 2048;                     // 2048
    float*  w1d   = Bw + 2048;                     // 64
    float*  ctrA  = w1d + 64;                      // B*N*64 = 1048576
    float*  nbrB  = ctrA + BB * NN * 64;           // B*N*64 = 1048576
    // pkey (RS*PK*B*N u32 = 33.5 MB) lives in d_out (67 MB): written by
    // knn_prefilter, read by knn_final, then fully overwritten by fuse_kernel.
    unsigned* pkey = (unsigned*)d_out;

    hipLaunchKernelGGL(p0_weights, dim3(1), dim3(256), 0, stream, W1, Aw, Bw, w1d);
    hipLaunchKernelGGL(p1_transpose, dim3(BB * NN / 256), dim3(256), 0, stream,
                       features, pT, sq32, sq64);
    hipLaunchKernelGGL(knn_prefilter, dim3(BB * NN / 256, RS), dim3(256), 0, stream,
                       pT, sq32, pkey);
    hipLaunchKernelGGL(knn_final, dim3(BB * NN / 64), dim3(64), 0, stream,
                       pT, sq64, pkey, fidx, fdist);
    hipLaunchKernelGGL(p2_proj, dim3(BB * NN * 64 / 256), dim3(256), 0, stream,
                       pT, Aw, Bw, ctrA, nbrB);
    hipLaunchKernelGGL(fuse_kernel, dim3(NN / 16, BB), dim3(256), 0, stream,
                       coords, features, knn_idx, knn_dist, W2, W3, W4, W5,
                       g1, b1, g2, b2, g3, b3, g4, b4, g5, b5,
                       ctrA, nbrB, w1d, fidx, fdist, out);
}

// Round 8
// 325.417 us; speedup vs baseline: 1.3145x; 1.3145x over previous
//
#include <hip/hip_runtime.h>
#include <math.h>

#define BB 4
#define NN 4096
#define KK 16
#define CIN 32
#define BN_INV 0.9999950000375f

#define RS 32    // candidate ranges per query
#define PCH 128  // candidates per range (NN/RS)
#define PK 8     // prefilter top-K per range
#define NK2 24   // candidates sent to fp64 rerank

typedef float f32x2 __attribute__((ext_vector_type(2)));

// ---------------- P0: derived W1 weights + padded W3/W4 copies ----------------
__global__ void p0_weights(const float* __restrict__ W1,
                           const float* __restrict__ W3, const float* __restrict__ W4,
                           float* __restrict__ Aw, float* __restrict__ Bw,
                           float* __restrict__ w1d,
                           float* __restrict__ W3p, float* __restrict__ W4p) {
    int t = threadIdx.x;
    for (int i = t; i < 64 * 32; i += 256) {
        int o = i >> 5, c = i & 31;
        Aw[i] = W1[o * 128 + c] - W1[o * 128 + 64 + c];
        Bw[i] = W1[o * 128 + 32 + c] + W1[o * 128 + 64 + c];
    }
    if (t < 64) {
        float s = 0.f;
        for (int c = 96; c < 128; ++c) s += W1[t * 128 + c];
        w1d[t] = s;
    }
    for (int i = t; i < 32 * 14; i += 256) {
        int r = i / 14, j = i - r * 14;
        W3p[i] = (j < 13) ? W3[r * 13 + j] : 0.f;
        W4p[i] = (j < 13) ? W4[r * 13 + j] : 0.f;
    }
}

// ---------------- P1: transpose features to [B,N,32] + fp32/fp64 norms ----------------
__global__ void p1_transpose(const float* __restrict__ f, float* __restrict__ pT,
                             float* __restrict__ sq32, double* __restrict__ sq64) {
    int g = blockIdx.x * 256 + threadIdx.x;  // b*N + n
    int b = g >> 12, n = g & (NN - 1);
    float v[CIN];
#pragma unroll
    for (int c = 0; c < CIN; ++c) v[c] = f[(b * CIN + c) * NN + n];
#pragma unroll
    for (int c = 0; c < CIN; ++c) pT[(size_t)g * CIN + c] = v[c];
    // sequential chain — BITWISE identical to knn_prefilter's per-lane dot chain
    float s32 = 0.f;
#pragma unroll
    for (int c = 0; c < CIN; ++c) s32 = fmaf(v[c], v[c], s32);
    sq32[g] = s32;
    // sequential fp64 chain — must match knn_final's rerank chains
    double s64 = 0.0;
#pragma unroll
    for (int c = 0; c < CIN; ++c) s64 = fma((double)v[c], (double)v[c], s64);
    sq64[g] = s64;
}

// ---------------- P2: per-point projections ctrA = A*p, nbrB = B*p ----------------
__global__ __launch_bounds__(256) void p2_proj(const float* __restrict__ pT,
                                               const float* __restrict__ Aw,
                                               const float* __restrict__ Bw,
                                               float* __restrict__ ctrA,
                                               float* __restrict__ nbrB) {
    __shared__ float sA[32 * 64], sB[32 * 64];
    for (int i = threadIdx.x; i < 2048; i += 256) {
        int o = i >> 5, c = i & 31;
        sA[c * 64 + o] = Aw[i];
        sB[c * 64 + o] = Bw[i];
    }
    __syncthreads();
    int g = blockIdx.x * 256 + threadIdx.x;  // (b*N+n)*64 + o
    int o = g & 63;
    int pn = g >> 6;
    const float* p = pT + (size_t)pn * 32;
    float a = 0.f, bb = 0.f;
#pragma unroll
    for (int c = 0; c < 32; ++c) {
        float pv = p[c];
        a = fmaf(sA[c * 64 + o], pv, a);
        bb = fmaf(sB[c * 64 + o], pv, bb);
    }
    ctrA[g] = a;
    nbrB[g] = bb;
}

// ---------------- KNN prefilter: 2 queries/thread packed in pk lanes ----------------
__global__ __launch_bounds__(256) void knn_prefilter(const float* __restrict__ pT,
                                                     const float* __restrict__ sq32,
                                                     unsigned* __restrict__ pkey) {
    __shared__ float tile[PCH * 32];   // 16 KB candidate tile
    __shared__ float tsq[PCH];
    int tid = threadIdx.x;
    int qbase = blockIdx.x * 512;
    int n0 = qbase + tid;          // query in lane .x
    int n1 = qbase + 256 + tid;    // query in lane .y
    int b = n0 >> 12;
    const float* pb = pT + ((size_t)(b << 12)) * 32;
    int m0 = blockIdx.y * PCH;

    {
        const float4* src = (const float4*)(pb + (size_t)m0 * 32);
        float4* dst = (float4*)tile;
#pragma unroll
        for (int i = 0; i < 4; ++i) dst[tid + 256 * i] = src[tid + 256 * i];
        if (tid < PCH) tsq[tid] = sq32[(b << 12) + m0 + tid];
    }

    f32x2 qv[32];  // channel c packed {qA[c], qB[c]}
    {
        const float4* qa = (const float4*)(pT + (size_t)n0 * 32);
        const float4* qb = (const float4*)(pT + (size_t)n1 * 32);
#pragma unroll
        for (int c4 = 0; c4 < 8; ++c4) {
            float4 ta = qa[c4], tb = qb[c4];
            qv[4 * c4 + 0] = (f32x2){ta.x, tb.x};
            qv[4 * c4 + 1] = (f32x2){ta.y, tb.y};
            qv[4 * c4 + 2] = (f32x2){ta.z, tb.z};
            qv[4 * c4 + 3] = (f32x2){ta.w, tb.w};
        }
    }
    f32x2 negsq = (f32x2){-sq32[n0], -sq32[n1]};
    unsigned keyA[PK], keyB[PK];
#pragma unroll
    for (int i = 0; i < PK; ++i) { keyA[i] = 0u; keyB[i] = 0u; }

    __syncthreads();

#pragma unroll 2
    for (int mm = 0; mm < PCH; ++mm) {
        const float4* row = (const float4*)(tile + mm * 32);  // wave-uniform broadcast
        f32x2 acc = (f32x2){0.f, 0.f};
#pragma unroll
        for (int c4 = 0; c4 < 8; ++c4) {
            float4 t = row[c4];
            acc = __builtin_elementwise_fma((f32x2){t.x, t.x}, qv[4 * c4 + 0], acc);
            acc = __builtin_elementwise_fma((f32x2){t.y, t.y}, qv[4 * c4 + 1], acc);
            acc = __builtin_elementwise_fma((f32x2){t.z, t.z}, qv[4 * c4 + 2], acc);
            acc = __builtin_elementwise_fma((f32x2){t.w, t.w}, qv[4 * c4 + 3], acc);
        }
        // per lane: d = fmaf(2, dot, (-sqn) - tsq); self -> exactly 0 (sequential
        // chain bitwise == p1's sq32 chain)
        float ts = tsq[mm];
        f32x2 bias = negsq - (f32x2){ts, ts};
        f32x2 d = __builtin_elementwise_fma((f32x2){2.f, 2.f}, acc, bias);
        int mkey = 4095 - (m0 + mm);
        {
            unsigned u = __float_as_uint(d.x);
            unsigned k32 = u ^ (unsigned)(((int)u >> 31) | 0x80000000);
            unsigned cv = (k32 & 0xFFFFF000u) | (unsigned)mkey;
#pragma unroll
            for (int j = 0; j < PK; ++j) {
                unsigned vj = keyA[j];
                unsigned hi = cv > vj ? cv : vj;
                unsigned lo = cv > vj ? vj : cv;
                keyA[j] = hi; cv = lo;
            }
        }
        {
            unsigned u = __float_as_uint(d.y);
            unsigned k32 = u ^ (unsigned)(((int)u >> 31) | 0x80000000);
            unsigned cv = (k32 & 0xFFFFF000u) | (unsigned)mkey;
#pragma unroll
            for (int j = 0; j < PK; ++j) {
                unsigned vj = keyB[j];
                unsigned hi = cv > vj ? cv : vj;
                unsigned lo = cv > vj ? vj : cv;
                keyB[j] = hi; cv = lo;
            }
        }
    }
    size_t base = (size_t)blockIdx.y * PK * (BB * NN);
#pragma unroll
    for (int i = 0; i < PK; ++i) {
        pkey[base + (size_t)i * (BB * NN) + n0] = keyA[i];
        pkey[base + (size_t)i * (BB * NN) + n1] = keyB[i];
    }
}

// ---------------- KNN final: key-select top-24, fp64 exact rerank -> top-16 ----------------
__global__ __launch_bounds__(64) void knn_final(const float* __restrict__ pT,
                                                const double* __restrict__ sq64,
                                                const unsigned* __restrict__ pkey,
                                                int* __restrict__ fidx,
                                                float* __restrict__ fdist) {
    int n = blockIdx.x * 64 + threadIdx.x;
    int b = n >> 12;
    const float* pb = pT + ((size_t)(b << 12)) * 32;
    const double* sqb = sq64 + (b << 12);

    unsigned sk[NK2];
#pragma unroll
    for (int i = 0; i < NK2; ++i) sk[i] = 0u;
    for (int r = 0; r < RS; ++r) {
        unsigned kv[PK];
#pragma unroll
        for (int k = 0; k < PK; ++k)
            kv[k] = pkey[(size_t)(r * PK + k) * (BB * NN) + n];  // coalesced batch
        for (int k = 0; k < PK; ++k) {
            unsigned cv = kv[k];
            if (__all(cv <= sk[NK2 - 1])) break;  // lane-keys descend within range
#pragma unroll
            for (int j = 0; j < NK2; ++j) {
                unsigned vj = sk[j];
                unsigned hi = cv > vj ? cv : vj;
                unsigned lo = cv > vj ? vj : cv;
                sk[j] = hi; cv = lo;
            }
        }
    }

    // fp64 exact rerank of the NK2 survivors
    double qv[32];
    const float4* q4 = (const float4*)(pT + (size_t)n * 32);
#pragma unroll
    for (int c4 = 0; c4 < 8; ++c4) {
        float4 t = q4[c4];
        qv[4 * c4] = (double)t.x; qv[4 * c4 + 1] = (double)t.y;
        qv[4 * c4 + 2] = (double)t.z; qv[4 * c4 + 3] = (double)t.w;
    }
    double sqn = 0.0;
#pragma unroll
    for (int c = 0; c < 32; ++c) sqn = fma(qv[c], qv[c], sqn);

    double dv[16];
    int di[16];
#pragma unroll
    for (int i = 0; i < 16; ++i) { dv[i] = -1e300; di[i] = 0x7fffffff; }
#pragma unroll
    for (int u = 0; u < NK2; ++u) {
        int m = 4095 - (int)(sk[u] & 0xFFFu);
        const float4* row = (const float4*)(pb + (size_t)m * 32);
        double dot = 0.0;
#pragma unroll
        for (int c4 = 0; c4 < 8; ++c4) {
            float4 t = row[c4];
            dot = fma((double)t.x, qv[4 * c4], dot);
            dot = fma((double)t.y, qv[4 * c4 + 1], dot);
            dot = fma((double)t.z, qv[4 * c4 + 2], dot);
            dot = fma((double)t.w, qv[4 * c4 + 3], dot);
        }
        double d = 2.0 * dot - sqn - sqb[m];  // self -> exactly 0
        if (d > dv[15] || (d == dv[15] && m < di[15])) {
            double cv = d; int ci = m;
#pragma unroll
            for (int j = 0; j < 16; ++j) {
                bool c = (cv > dv[j]) || (cv == dv[j] && ci < di[j]);
                double nv = c ? cv : dv[j]; double nc = c ? dv[j] : cv;
                int ni = c ? ci : di[j];    int nj = c ? di[j] : ci;
                dv[j] = nv; cv = nc; di[j] = ni; ci = nj;
            }
        }
    }
#pragma unroll
    for (int i = 0; i < 16; ++i) {
        fdist[(size_t)n * 16 + i] = (float)dv[i];
        fidx[(size_t)n * 16 + i] = di[i];
    }
}

// ---------------- Fused pipeline: scalar-uniform weights + pk math ----------------
__global__ __launch_bounds__(256, 4) void fuse_kernel(
    const float* __restrict__ coords, const float* __restrict__ feat,
    const int* __restrict__ knn_idx, const float* __restrict__ knn_dist,
    const float* __restrict__ W2, const float* __restrict__ W3p,
    const float* __restrict__ W4p, const float* __restrict__ W5,
    const float* __restrict__ g1, const float* __restrict__ b1,
    const float* __restrict__ g2, const float* __restrict__ b2,
    const float* __restrict__ g3, const float* __restrict__ b3,
    const float* __restrict__ g4, const float* __restrict__ b4,
    const float* __restrict__ g5, const float* __restrict__ b5,
    const float* __restrict__ ctrA, const float* __restrict__ nbrB,
    const float* __restrict__ w1d, const int* __restrict__ fidx,
    const float* __restrict__ fdist, float* __restrict__ out) {
    int g = blockIdx.x * 256 + threadIdx.x;
    int k = g & 15;
    int n = (g >> 4) & (NN - 1);
    int b = g >> 16;
    int pn = b * NN + n;

    // early gathers
    int fnb = fidx[(size_t)pn * 16 + k];
    float fd = fdist[(size_t)pn * 16 + k];
    int cnb = knn_idx[(size_t)pn * 16 + k];
    float kd = knn_dist[(size_t)pn * 16 + k];
    const f32x2* nB2 = (const f32x2*)(nbrB + ((size_t)b * NN + fnb) * 64);
    const f32x2* cA2 = (const f32x2*)(ctrA + (size_t)pn * 64);
    float cq[3], cn_[3];
#pragma unroll
    for (int j = 0; j < 3; ++j) cq[j] = coords[(size_t)pn * 3 + j];
#pragma unroll
    for (int j = 0; j < 3; ++j) cn_[j] = coords[((size_t)b * NN + cnb) * 3 + j];

    // features_knn (64) = leaky(BN(W1 . edge)) = max(v, 0.2v)
    const f32x2* wd2 = (const f32x2*)w1d;
    const f32x2* g12 = (const f32x2*)g1;
    const f32x2* b12 = (const f32x2*)b1;
    f32x2 fdp = (f32x2){fd, fd};
    f32x2 bni = (f32x2){BN_INV, BN_INV};
    f32x2 fkp[32];
#pragma unroll
    for (int o = 0; o < 32; ++o) {
        f32x2 y = __builtin_elementwise_fma(wd2[o], fdp, cA2[o] + nB2[o]);
        f32x2 v = __builtin_elementwise_fma(g12[o] * bni, y, b12[o]);
        fkp[o] = __builtin_elementwise_max(v, v * (f32x2){0.2f, 0.2f});
    }

    // features_offset (3) = elu(BN(W2 . fk)); build concat_point pairs
    f32x2 cpp[7];
    float pe[3];
#pragma unroll
    for (int j = 0; j < 3; ++j) {
        const f32x2* w2r = (const f32x2*)(W2 + j * 64);
        f32x2 ap = (f32x2){0.f, 0.f};
#pragma unroll
        for (int i = 0; i < 32; ++i) ap = __builtin_elementwise_fma(w2r[i], fkp[i], ap);
        float a = ap.x + ap.y;
        float t = fmaf(g2[j] * BN_INV, a, b2[j]);
        t = t > 0.f ? t : __expf(t) - 1.f;
        pe[j] = t + cq[j];
    }
    cpp[0] = (f32x2){cq[0], cq[1]};
    cpp[1] = (f32x2){cq[2], cn_[0]};
    cpp[2] = (f32x2){cn_[1], cn_[2]};
    cpp[3] = (f32x2){cq[0] - cn_[0], cq[1] - cn_[1]};
    cpp[4] = (f32x2){cq[2] - cn_[2], kd};
    cpp[5] = (f32x2){pe[0], pe[1]};
    cpp[6] = (f32x2){pe[2], 0.f};

    // point_offset -> features_e ; out_point
    size_t outbase = (((size_t)b * 64) * NN + n) * 16 + k;  // c stride NN*16
    f32x2 fep[16];
#pragma unroll
    for (int c2 = 0; c2 < 16; ++c2) {
        float fv[2];
#pragma unroll
        for (int h = 0; h < 2; ++h) {
            int c = 2 * c2 + h;
            const f32x2* w3r = (const f32x2*)(W3p + c * 14);
            const f32x2* w4r = (const f32x2*)(W4p + c * 14);
            f32x2 a3p = (f32x2){0.f, 0.f}, a4p = (f32x2){0.f, 0.f};
#pragma unroll
            for (int j = 0; j < 7; ++j) {
                a3p = __builtin_elementwise_fma(w3r[j], cpp[j], a3p);
                a4p = __builtin_elementwise_fma(w4r[j], cpp[j], a4p);
            }
            float a3 = a3p.x + a3p.y, a4 = a4p.x + a4p.y;
            float po = fmaf(g3[c] * BN_INV, a3, b3[c]);
            po = po > 0.f ? po : __expf(po) - 1.f;
            fv[h] = po + feat[((size_t)b * 32 + c) * NN + n];
            float op = fmaf(g4[c] * BN_INV, a4, b4[c]);
            op = op > 0.f ? op : __expf(op) - 1.f;
            out[outbase + (size_t)c * (NN * 16)] = op;
        }
        fep[c2] = (f32x2){fv[0], fv[1]};
    }

    // out_feature = elu(BN(W5 . [fk(64), fe(32)]))
#pragma unroll
    for (int c = 0; c < 32; ++c) {
        const f32x2* w5r = (const f32x2*)(W5 + c * 96);
        f32x2 ap = (f32x2){0.f, 0.f};
#pragma unroll
        for (int i = 0; i < 32; ++i) ap = __builtin_elementwise_fma(w5r[i], fkp[i], ap);
#pragma unroll
        for (int i = 0; i < 16; ++i) ap = __builtin_elementwise_fma(w5r[32 + i], fep[i], ap);
        float a5 = ap.x + ap.y;
        float v = fmaf(g5[c] * BN_INV, a5, b5[c]);
        v = v > 0.f ? v : __expf(v) - 1.f;
        out[outbase + (size_t)(32 + c) * (NN * 16)] = v;
    }
}

extern "C" void kernel_launch(void* const* d_in, const int* in_sizes, int n_in,
                              void* d_out, int out_size, void* d_ws, size_t ws_size,
                              hipStream_t stream) {
    const float* coords   = (const float*)d_in[0];
    const float* features = (const float*)d_in[1];
    const int*   knn_idx  = (const int*)d_in[2];
    const float* knn_dist = (const float*)d_in[3];
    const float* W1 = (const float*)d_in[4];
    const float* W2 = (const float*)d_in[5];
    const float* W3 = (const float*)d_in[6];
    const float* W4 = (const float*)d_in[7];
    const float* W5 = (const float*)d_in[8];
    const float* g1 = (const float*)d_in[9];
    const float* b1 = (const float*)d_in[10];
    const float* g2 = (const float*)d_in[11];
    const float* b2 = (const float*)d_in[12];
    const float* g3 = (const float*)d_in[13];
    const float* b3 = (const float*)d_in[14];
    const float* g4 = (const float*)d_in[15];
    const float* b4 = (const float*)d_in[16];
    const float* g5 = (const float*)d_in[17];
    const float* b5 = (const float*)d_in[18];
    float* out = (float*)d_out;

    // workspace layout (float slots)
    float*  pT    = (float*)d_ws;                  // 524288
    float*  sq32  = pT + BB * NN * 32;             // 16384
    double* sq64  = (double*)(sq32 + BB * NN);     // 16384 doubles (32768 slots)
    float*  fdist = (float*)(sq64 + BB * NN);      // 262144
    int*    fidx  = (int*)(fdist + BB * NN * 16);  // 262144
    float*  Aw    = (float*)(fidx + BB * NN * 16); // 2048
    float*  Bw    = Aw + 2048;                     // 2048
    float*  w1d   = Bw + 2048;                     // 64
    float*  W3p   = w1d + 64;                      // 448 (pad to 512)
    float*  W4p   = W3p + 512;                     // 448 (pad to 512)
    float*  ctrA  = W4p + 512;                     // B*N*64 = 1048576
    float*  nbrB  = ctrA + BB * NN * 64;           // B*N*64 = 1048576
    // pkey (RS*PK*B*N u32 = 16.8 MB) lives in d_out (67 MB): written by
    // knn_prefilter, read by knn_final, then fully overwritten by fuse_kernel.
    unsigned* pkey = (unsigned*)d_out;

    hipLaunchKernelGGL(p0_weights, dim3(1), dim3(256), 0, stream,
                       W1, W3, W4, Aw, Bw, w1d, W3p, W4p);
    hipLaunchKernelGGL(p1_transpose, dim3(BB * NN / 256), dim3(256), 0, stream,
                       features, pT, sq32, sq64);
    hipLaunchKernelGGL(knn_prefilter, dim3(BB * NN / 512, RS), dim3(256), 0, stream,
                       pT, sq32, pkey);
    hipLaunchKernelGGL(knn_final, dim3(BB * NN / 64), dim3(64), 0, stream,
                       pT, sq64, pkey, fidx, fdist);
    hipLaunchKernelGGL(p2_proj, dim3(BB * NN * 64 / 256), dim3(256), 0, stream,
                       pT, Aw, Bw, ctrA, nbrB);
    hipLaunchKernelGGL(fuse_kernel, dim3(BB * NN * KK / 256), dim3(256), 0, stream,
                       coords, features, knn_idx, knn_dist, W2, W3p, W4p, W5,
                       g1, b1, g2, b2, g3, b3, g4, b4, g5, b5,
                       ctrA, nbrB, w1d, fidx, fdist, out);
}